// Round 9
// baseline (1100.508 us; speedup 1.0000x reference)
//
#include <hip/hip_runtime.h>
#include <hip/hip_bf16.h>

#define N_NODES 100000
#define N_EDGES 3200000
#define IN_DIM 128
#define HIDDEN 64
#define N_GRAPHS 512
#define SCAN_BLOCKS 391   // ceil(N_NODES/256)
#define EPW 256           // edges per wave strip (N_EDGES % EPW == 0)
#define PULL_BLOCKS (N_EDGES / EPW / 4)   // 3125

typedef __hip_bfloat16 bf16;
__device__ __forceinline__ float b2f(bf16 v) { return __bfloat162float(v); }

// ---------------- CSR build ----------------
__global__ void deg_count_kernel(const int* __restrict__ dst, int* __restrict__ deg) {
    int e = blockIdx.x * blockDim.x + threadIdx.x;
    if (e < N_EDGES) atomicAdd(&deg[dst[e]], 1);
}

__global__ __launch_bounds__(256) void scan1_kernel(const int* __restrict__ cnt,
                                                    int* __restrict__ partials) {
    __shared__ int sd[256];
    int t = threadIdx.x;
    int i = blockIdx.x * 256 + t;
    sd[t] = (i < N_NODES) ? cnt[i] : 0;
    __syncthreads();
    for (int s = 128; s > 0; s >>= 1) {
        if (t < s) sd[t] += sd[t + s];
        __syncthreads();
    }
    if (t == 0) partials[blockIdx.x] = sd[0];
}

__global__ __launch_bounds__(512) void scan2_kernel(int* __restrict__ partials) {
    __shared__ int sd[512];
    int t = threadIdx.x;
    int v = (t < SCAN_BLOCKS) ? partials[t] : 0;
    sd[t] = v;
    __syncthreads();
    for (int off = 1; off < 512; off <<= 1) {
        int u = (t >= off) ? sd[t - off] : 0;
        __syncthreads();
        sd[t] += u;
        __syncthreads();
    }
    partials[t] = sd[t] - v;   // exclusive prefix
}

__global__ __launch_bounds__(256) void scan3_kernel(const int* __restrict__ cnt,
                                                    const int* __restrict__ partials,
                                                    int* __restrict__ base,
                                                    float* __restrict__ dis) {
    __shared__ int sd[256];
    int t = threadIdx.x;
    int i = blockIdx.x * 256 + t;
    int v = (i < N_NODES) ? cnt[i] : 0;
    sd[t] = v;
    __syncthreads();
    for (int off = 1; off < 256; off <<= 1) {
        int u = (t >= off) ? sd[t - off] : 0;
        __syncthreads();
        sd[t] += u;
        __syncthreads();
    }
    if (i < N_NODES) {
        base[i] = partials[blockIdx.x] + sd[t] - v;     // exclusive
        dis[i] = rsqrtf((float)(v + 1));                // +1 self-loop
    }
    if (blockIdx.x == 0 && t == 0) base[N_NODES] = N_EDGES;
}

// 4 B scatter: only src. Slot via atomicSub on deg_cnt (free after scans).
__global__ void fill_kernel(const int* __restrict__ src, const int* __restrict__ dst,
                            const int* __restrict__ base, int* __restrict__ deg_cnt,
                            int* __restrict__ srcs) {
    int e = blockIdx.x * blockDim.x + threadIdx.x;
    if (e < N_EDGES) {
        int d = dst[e];
        int slot = atomicSub(&deg_cnt[d], 1) - 1;   // unique in [0, deg)
        srcs[base[d] + slot] = src[e];
    }
}

// dstid[e] = owning node, generated sequentially (coalesced) from base.
__global__ __launch_bounds__(256) void expand_kernel(const int* __restrict__ base,
                                                     int* __restrict__ dstid) {
    int w = threadIdx.x >> 6, lane = threadIdx.x & 63;
    int node = blockIdx.x * 4 + w;
    if (node >= N_NODES) return;
    int beg = base[node], end = base[node + 1];
    for (int e = beg + lane; e < end; e += 64) dstid[e] = node;
}

// ---------------- GEMM: hd = bf16((in@W)*dis), acc = f32 same (self-loop init)
// NOTE: in gemm2, `in` aliases `acc` (in-place row transform) — no __restrict__
// on those two; each row's reads complete before its stores in program order.
template <int K>
__global__ __launch_bounds__(256) void gemm_kernel(
        const float* in, const float* __restrict__ W,
        const float* __restrict__ dis, bf16* __restrict__ hd,
        float* acc) {
    int tid = threadIdx.x;
    int lane = tid & 63;
    float Wr[K];
    #pragma unroll
    for (int k = 0; k < K; ++k) Wr[k] = W[k * HIDDEN + lane];   // coalesced
    int w = __builtin_amdgcn_readfirstlane(tid >> 6);           // provably uniform
    int wave = blockIdx.x * 4 + w;
    int nw = gridDim.x * 4;
    for (int n0 = wave * 4; n0 < N_NODES; n0 += nw * 4) {
        const float* xr = in + (size_t)n0 * K;
        float a0 = 0.f, a1 = 0.f, a2 = 0.f, a3 = 0.f;
        #pragma unroll
        for (int k = 0; k < K; ++k) {
            float wv = Wr[k];
            a0 = fmaf(xr[k],         wv, a0);
            a1 = fmaf(xr[K + k],     wv, a1);
            a2 = fmaf(xr[2 * K + k], wv, a2);
            a3 = fmaf(xr[3 * K + k], wv, a3);
        }
        float h0 = a0 * dis[n0];
        float h1 = a1 * dis[n0 + 1];
        float h2 = a2 * dis[n0 + 2];
        float h3 = a3 * dis[n0 + 3];
        bf16* o = hd + (size_t)n0 * HIDDEN + lane;
        o[0]          = __float2bfloat16(h0);
        o[HIDDEN]     = __float2bfloat16(h1);
        o[2 * HIDDEN] = __float2bfloat16(h2);
        o[3 * HIDDEN] = __float2bfloat16(h3);
        float* ap = acc + (size_t)n0 * HIDDEN + lane;
        ap[0]          = h0;
        ap[HIDDEN]     = h1;
        ap[2 * HIDDEN] = h2;
        ap[3 * HIDDEN] = h3;
    }
}

// ---------------- flat edge-centric pull ----------------
// Wave owns edges [wave*EPW, wave*EPW+EPW). csr chunks loaded up-front;
// 8-gather ping-pong pipeline; lane=channel running sum; atomic row flush on
// (wave-uniform) dst change. No per-node load chain anywhere.
__global__ __launch_bounds__(256) void pull_kernel(
        const bf16* __restrict__ hd, const int* __restrict__ srcs,
        const int* __restrict__ dstid, float* __restrict__ acc) {
    int w = threadIdx.x >> 6, lane = threadIdx.x & 63;
    int wave = blockIdx.x * 4 + w;
    size_t e0 = (size_t)wave * EPW;
    int s0 = srcs[e0 + lane];
    int s1 = srcs[e0 + 64 + lane];
    int s2 = srcs[e0 + 128 + lane];
    int s3 = srcs[e0 + 192 + lane];
    int d0 = dstid[e0 + lane];
    int d1 = dstid[e0 + 64 + lane];
    int d2 = dstid[e0 + 128 + lane];
    int d3 = dstid[e0 + 192 + lane];
    float G0[8], G1[8];
    int cur = -1;
    float A = 0.f;
    // prolog: issue group 0
    #pragma unroll
    for (int i = 0; i < 8; ++i) {
        int s = __shfl(s0, i);
        G0[i] = b2f(hd[(size_t)s * HIDDEN + lane]);
    }
    #pragma unroll
    for (int g = 0; g < 32; ++g) {
        if (g < 31) {   // issue group g+1 into the other buffer
            #pragma unroll
            for (int i = 0; i < 8; ++i) {
                int t = (g + 1) * 8 + i;
                int ch = t >> 6;
                int sx = ch == 0 ? s0 : ch == 1 ? s1 : ch == 2 ? s2 : s3;
                int s = __shfl(sx, t & 63);
                float* G = (g & 1) ? G0 : G1;
                G[i] = b2f(hd[(size_t)s * HIDDEN + lane]);
            }
        }
        #pragma unroll
        for (int i = 0; i < 8; ++i) {   // consume group g
            int t = g * 8 + i;
            int ch = t >> 6;
            int dx = ch == 0 ? d0 : ch == 1 ? d1 : ch == 2 ? d2 : d3;
            int d = __shfl(dx, t & 63);
            float* G = (g & 1) ? G1 : G0;
            if (d != cur) {   // wave-uniform
                if (cur >= 0) atomicAdd(&acc[(size_t)cur * HIDDEN + lane], A);
                A = 0.f;
                cur = d;
            }
            A += G[i];
        }
    }
    if (cur >= 0) atomicAdd(&acc[(size_t)cur * HIDDEN + lane], A);
}

// ---------------- finalize layer 1: acc = relu(dis*acc + b1), in place -------
__global__ void finalize1_kernel(float* __restrict__ acc, const float* __restrict__ dis,
                                 const float* __restrict__ bias) {
    int i = blockIdx.x * blockDim.x + threadIdx.x;   // float4 granularity
    int n4 = N_NODES * HIDDEN / 4;
    if (i < n4) {
        int node = (i * 4) >> 6;
        int ch = (i * 4) & 63;
        float dn = dis[node];
        float4 v = ((float4*)acc)[i];
        float4 bb = *(const float4*)(bias + ch);
        v.x = fmaf(dn, v.x, bb.x); v.y = fmaf(dn, v.y, bb.y);
        v.z = fmaf(dn, v.z, bb.z); v.w = fmaf(dn, v.w, bb.w);
        v.x = v.x > 0.f ? v.x : 0.f;
        v.y = v.y > 0.f ? v.y : 0.f;
        v.z = v.z > 0.f ? v.z : 0.f;
        v.w = v.w > 0.f ? v.w : 0.f;
        ((float4*)acc)[i] = v;
    }
}

// ---------------- finalize layer 2: relu(dis*acc+b2) -> mean-pool atomics ----
__global__ __launch_bounds__(256) void finalize2_kernel(
        const float* __restrict__ acc, const float* __restrict__ dis,
        const float* __restrict__ bias, const int* __restrict__ batch,
        float* __restrict__ pool, float* __restrict__ cnt) {
    int w = threadIdx.x >> 6, lane = threadIdx.x & 63;
    int node = blockIdx.x * 4 + w;
    if (node >= N_NODES) return;
    float v = fmaf(dis[node], acc[(size_t)node * HIDDEN + lane], bias[lane]);
    v = v > 0.f ? v : 0.f;
    int g = batch[node];
    atomicAdd(&pool[g * HIDDEN + lane], v);
    if (lane == 0) atomicAdd(&cnt[g], 1.0f);
}

__global__ void final_kernel(const float* __restrict__ pool,
                             const float* __restrict__ cnt,
                             float* __restrict__ out) {
    int i = blockIdx.x * blockDim.x + threadIdx.x;
    if (i < N_GRAPHS * HIDDEN) {
        float c = cnt[i >> 6];
        c = c > 1.0f ? c : 1.0f;
        out[i] = pool[i] / c;
    }
}

extern "C" void kernel_launch(void* const* d_in, const int* in_sizes, int n_in,
                              void* d_out, int out_size, void* d_ws, size_t ws_size,
                              hipStream_t stream) {
    const float* x  = (const float*)d_in[0];
    const float* W1 = (const float*)d_in[1];
    const float* b1 = (const float*)d_in[2];
    const float* W2 = (const float*)d_in[3];
    const float* b2 = (const float*)d_in[4];
    const int* edge_index = (const int*)d_in[5];
    const int* batch      = (const int*)d_in[6];
    float* out = (float*)d_out;
    (void)in_sizes; (void)n_in; (void)out_size; (void)ws_size;

    char* ws = (char*)d_ws;
    int*   deg_cnt  = (int*)  (ws + 0);         // 400000
    float* pool     = (float*)(ws + 400000);    // 131072
    float* cnt      = (float*)(ws + 531072);    // 2048   (zero region ends 533120)
    int*   partials = (int*)  (ws + 533120);    // 2048
    float* dis      = (float*)(ws + 535168);    // 400000
    int*   base     = (int*)  (ws + 935168);    // 400032 (padded)
    int*   srcs     = (int*)  (ws + 1335200);   // 12800000
    int*   dstid    = (int*)  (ws + 14135200);  // 12800000
    bf16*  hd       = (bf16*) (ws + 26935200);  // 12800000
    float* acc      = (float*)(ws + 39735200);  // 25600000 -> ends 65335200

    const int* srcv = edge_index;            // edge_index[0]
    const int* dstv = edge_index + N_EDGES;  // edge_index[1]

    // zero: deg_cnt, pool, cnt (contiguous region)
    hipMemsetAsync(ws, 0, 533120, stream);

    // CSR build (src-only 4 B entries; dstid generated sequentially)
    deg_count_kernel<<<(N_EDGES + 255) / 256, 256, 0, stream>>>(dstv, deg_cnt);
    scan1_kernel<<<SCAN_BLOCKS, 256, 0, stream>>>(deg_cnt, partials);
    scan2_kernel<<<1, 512, 0, stream>>>(partials);
    scan3_kernel<<<SCAN_BLOCKS, 256, 0, stream>>>(deg_cnt, partials, base, dis);
    fill_kernel<<<(N_EDGES + 255) / 256, 256, 0, stream>>>(srcv, dstv, base, deg_cnt, srcs);
    expand_kernel<<<(N_NODES + 3) / 4, 256, 0, stream>>>(base, dstid);

    // layer 1
    gemm_kernel<IN_DIM><<<1024, 256, 0, stream>>>(x, W1, dis, hd, acc);
    pull_kernel<<<PULL_BLOCKS, 256, 0, stream>>>(hd, srcs, dstid, acc);
    finalize1_kernel<<<(N_NODES * HIDDEN / 4 + 255) / 256, 256, 0, stream>>>(acc, dis, b1);

    // layer 2 (gemm reads act from acc and re-inits acc in place, per-row safe)
    gemm_kernel<HIDDEN><<<1024, 256, 0, stream>>>(acc, W2, dis, hd, acc);
    pull_kernel<<<PULL_BLOCKS, 256, 0, stream>>>(hd, srcs, dstid, acc);
    finalize2_kernel<<<(N_NODES + 3) / 4, 256, 0, stream>>>(acc, dis, b2, batch, pool, cnt);

    final_kernel<<<(N_GRAPHS * HIDDEN + 255) / 256, 256, 0, stream>>>(pool, cnt, out);
}